// Round 4
// baseline (441.113 us; speedup 1.0000x reference)
//
#include <hip/hip_runtime.h>
#include <stdint.h>

// Problem constants
#define N_B   32
#define C_INN 8
#define L_IN  4096
#define C_LAT 64
#define K_EMB 512
#define E_DIM 64
#define L_OUT 2049                 // (4096 + 2*2 - 4)/2 + 1
#define M_ROWS (N_B * L_OUT)       // 65568

// d_out layout (flat float32, reference return order)
#define SZ_XREC (N_B * C_INN * L_IN)     // 1048576
#define SZ_ZE   (N_B * C_LAT * L_OUT)    // 4196352
#define OFF_XREC 0
#define OFF_ZE   (SZ_XREC)
#define OFF_ZQ   (OFF_ZE + SZ_ZE)
#define OFF_IDX  (OFF_ZQ + SZ_ZE)

// ---------------------------------------------------------------------------
// Encode: z_e[n][c][t] = conv_b[c] + sum_{ci,k} x[n][ci][2t-2+k] * conv_w[c][ci][k]
// Round 4: 2304 blocks = 32 n x 9 t-slices x 8 channel-groups (9 blocks/CU;
// round 3's 288 blocks = 1.1 block/CU was latency-starved). Each lane: one t,
// 32 x-taps in registers, 8 output channels (256 FMA).
// ---------------------------------------------------------------------------
__global__ __launch_bounds__(256) void encode_kernel(
    const float* __restrict__ x, const float* __restrict__ w,
    const float* __restrict__ b, float* __restrict__ z_e)
{
    const int blk   = blockIdx.x;        // 0..2303
    const int n     = blk / 72;
    const int rem   = blk - n * 72;
    const int slice = rem >> 3;          // 0..8
    const int cg    = rem & 7;           // channel group: c = cg*8 .. cg*8+7
    const int t     = slice * 256 + threadIdx.x;   // 0..2303
    const bool valid = (t < L_OUT);

    const float* xrow = x + (size_t)n * (C_INN * L_IN);

    // x taps: xi = 2t-2 .. 2t+1 per ci
    float xv[C_INN][4];
    const bool fast = (t >= 1 && t <= 2047);  // 2t-2 >= 0 and 2t+1 <= 4095
    if (fast) {
#pragma unroll
        for (int ci = 0; ci < C_INN; ++ci) {
            float4 v = *(const float4*)(xrow + ci * L_IN + (2 * t - 2));
            xv[ci][0] = v.x; xv[ci][1] = v.y; xv[ci][2] = v.z; xv[ci][3] = v.w;
        }
    } else {
#pragma unroll
        for (int ci = 0; ci < C_INN; ++ci) {
#pragma unroll
            for (int k = 0; k < 4; ++k) {
                int xi = 2 * t - 2 + k;
                int xc = min(max(xi, 0), L_IN - 1);
                float v = valid ? xrow[ci * L_IN + xc] : 0.0f;
                xv[ci][k] = (xi >= 0 && xi < L_IN) ? v : 0.0f;
            }
        }
    }

    float* zcol = z_e + (size_t)n * (C_LAT * L_OUT) + t;

#pragma unroll
    for (int cj = 0; cj < 8; ++cj) {
        const int c = cg * 8 + cj;
        float a = b[c];
#pragma unroll
        for (int ci = 0; ci < C_INN; ++ci) {
            const float* wp = w + (c * C_INN + ci) * 4;  // wave-uniform
#pragma unroll
            for (int k = 0; k < 4; ++k) a += xv[ci][k] * wp[k];
        }
        if (valid) zcol[(size_t)c * L_OUT] = a;
    }
}

// ---------------------------------------------------------------------------
// Quantize: per row r=(n,t), argmin_k( 0.5*||cb_k||^2 - z_r . cb_k ).
// Round 4 restructure. Rounds 1-3 were stuck at ~112 us regardless of register
// strategy: the inner loop issued one broadcast global_load_dword per FMA
// (L1 retires ~1 load-instr/cyc/CU -> ~2.5 issue slots per useful FMA).
// New structure:
//   - z tile (64 rows x 64 d) in LDS, float4-interleaved [d4][row] so
//     ds_read_b128 with 16B lane stride is conflict-free.
//   - codes tiled x16 with 16 fp32 accumulators; codebook read as UNIFORM
//     float4 (dwordx4): 4 FMAs per load instr instead of 1.
//   - per d4 step: 1 ds_read_b128 + 16 uniform loads + 64 FMAs -> FMA-bound.
// Exact fp32 math, ascending-k compare preserves first-occurrence tie-break.
// ---------------------------------------------------------------------------
__global__ __launch_bounds__(256, 4) void quantize_kernel(
    const float* __restrict__ z_e, const float* __restrict__ cb,
    float* __restrict__ z_q, float* __restrict__ idx_out)
{
    __shared__ float s_cbh[K_EMB];                  // 0.5*||cb_k||^2  (2 KB)
    __shared__ float4 s_z4[16 * 64];                // z tile [d4][row] (16 KB)
    __shared__ unsigned long long s_best[4][64];    // (2 KB)

    const int tid  = threadIdx.x;
    const int wave = tid >> 6;
    const int lane = tid & 63;
    const int wq   = __builtin_amdgcn_readfirstlane(wave);  // wave-uniform

    // 0.5*||cb||^2 into LDS (each thread: 2 codes)
    for (int k = tid; k < K_EMB; k += 256) {
        const float4* cp = (const float4*)(cb + (size_t)k * E_DIM);
        float s = 0.0f;
#pragma unroll
        for (int d = 0; d < E_DIM / 4; ++d) {
            float4 v = cp[d];
            s += v.x * v.x + v.y * v.y + v.z * v.z + v.w * v.w;
        }
        s_cbh[k] = 0.5f * s;
    }

    // stage z tile: thread (row = tid&63, chans 16*(tid>>6)..+16)
    {
        const int  rl     = lane;
        const int  cbase  = wave * 16;
        const int  r      = blockIdx.x * 64 + rl;
        const bool act    = (r < M_ROWS);
        const unsigned rr = act ? (unsigned)r : 0u;
        const unsigned n  = rr / 2049u;
        const unsigned t  = rr - n * 2049u;
        const float* zp   = z_e + (size_t)n * (C_LAT * L_OUT) + t;
        float* sz = (float*)s_z4;
#pragma unroll
        for (int j = 0; j < 16; ++j) {
            const int c = cbase + j;
            const float v = zp[(size_t)c * L_OUT];   // coalesced across lanes
            sz[((c >> 2) * 64 + rl) * 4 + (c & 3)] = v;
        }
    }
    __syncthreads();

    const int  r      = blockIdx.x * 64 + lane;
    const bool active = (r < M_ROWS);
    const unsigned rr = active ? (unsigned)r : 0u;
    const unsigned n  = rr / 2049u;
    const unsigned t  = rr - n * 2049u;

    const int k0 = wq * 128;
    float best_m = INFINITY;
    int   best_k = 0;

    for (int kt = 0; kt < 8; ++kt) {
        const int cbase = k0 + kt * 16;
        float acc[16];
#pragma unroll
        for (int j = 0; j < 16; ++j) acc[j] = 0.0f;

#pragma unroll 4
        for (int d4 = 0; d4 < 16; ++d4) {
            const float4 zv = s_z4[d4 * 64 + lane];
#pragma unroll
            for (int j = 0; j < 16; ++j) {
                const float4 cv =
                    *(const float4*)(cb + (size_t)(cbase + j) * E_DIM + d4 * 4);
                acc[j] += zv.x * cv.x + zv.y * cv.y + zv.z * cv.z + zv.w * cv.w;
            }
        }
#pragma unroll
        for (int j = 0; j < 16; ++j) {
            const float m = s_cbh[cbase + j] - acc[j];
            if (m < best_m) { best_m = m; best_k = cbase + j; }
        }
    }

    // pack: order-preserving float bits in high 32, k in low 32
    unsigned um = __float_as_uint(best_m);
    um = (um & 0x80000000u) ? ~um : (um | 0x80000000u);
    unsigned long long packed =
        ((unsigned long long)um << 32) | (unsigned)best_k;
    if (!active) packed = ~0ULL;
    s_best[wave][lane] = packed;
    __syncthreads();

    unsigned long long p  = s_best[0][lane];
    unsigned long long q1 = s_best[1][lane];
    unsigned long long q2 = s_best[2][lane];
    unsigned long long q3 = s_best[3][lane];
    p = (q1 < p) ? q1 : p;
    p = (q2 < p) ? q2 : p;
    p = (q3 < p) ? q3 : p;
    const int fk = (int)(unsigned)p;

    if (active) {
        const float* csel = cb + (size_t)fk * E_DIM;
        float* zq = z_q + ((size_t)(n * C_LAT + wave * 16)) * L_OUT + t;
#pragma unroll
        for (int j = 0; j < 16; ++j)
            zq[(size_t)j * L_OUT] = csel[wave * 16 + j];
        if (wave == 0) idx_out[r] = (float)fk;
    }
}

// ---------------------------------------------------------------------------
// Decode (ConvTranspose1d): x_rec[n][co][t] = tconv_b[co]
//   + sum_{ci,s,k: t = 2s-2+k} z_q[n][ci][s] * tconv_w[ci][co][k]
// Round 4: 2 output channels per block (z_q loads reused x2) -> 1024 blocks
// (n x 4 co-pairs x 8 s-chunks), one s per lane.
// ---------------------------------------------------------------------------
__global__ __launch_bounds__(256) void decode_kernel(
    const float* __restrict__ zq, const float* __restrict__ w,
    const float* __restrict__ b, float* __restrict__ xr)
{
    const int blk   = blockIdx.x;           // 0..1023
    const int chunk = blk & 7;
    const int cp    = (blk >> 3) & 3;
    const int n     = blk >> 5;
    const int s     = chunk * 256 + threadIdx.x;   // 0..2047
    const int co0   = cp * 2, co1 = co0 + 1;

    const float* zn = zq + (size_t)n * (C_LAT * L_OUT) + s;
    float e0 = b[co0], o0 = e0;
    float e1 = b[co1], o1 = e1;

#pragma unroll 4
    for (int ci = 0; ci < C_LAT; ++ci) {
        const float z0 = zn[(size_t)ci * L_OUT];
        const float z1 = zn[(size_t)ci * L_OUT + 1];
        const float* wp0 = w + (ci * C_INN + co0) * 4;   // wave-uniform
        const float* wp1 = wp0 + 4;
        e0 += z0 * wp0[2] + z1 * wp0[0];
        o0 += z0 * wp0[3] + z1 * wp0[1];
        e1 += z0 * wp1[2] + z1 * wp1[0];
        o1 += z0 * wp1[3] + z1 * wp1[1];
    }

    float* x0 = xr + ((size_t)(n * C_INN + co0)) * L_IN;
    float* x1 = xr + ((size_t)(n * C_INN + co1)) * L_IN;
    *(float2*)(x0 + 2 * s) = make_float2(e0, o0);   // 8B aligned
    *(float2*)(x1 + 2 * s) = make_float2(e1, o1);
}

// ---------------------------------------------------------------------------
extern "C" void kernel_launch(void* const* d_in, const int* in_sizes, int n_in,
                              void* d_out, int out_size, void* d_ws, size_t ws_size,
                              hipStream_t stream) {
    const float* x        = (const float*)d_in[0];
    const float* conv_w   = (const float*)d_in[1];
    const float* conv_b   = (const float*)d_in[2];
    const float* codebook = (const float*)d_in[3];
    const float* tconv_w  = (const float*)d_in[4];
    const float* tconv_b  = (const float*)d_in[5];

    float* out   = (float*)d_out;
    float* x_rec = out + OFF_XREC;
    float* z_e   = out + OFF_ZE;
    float* z_q   = out + OFF_ZQ;
    float* idxs  = out + OFF_IDX;

    encode_kernel<<<N_B * 72, 256, 0, stream>>>(x, conv_w, conv_b, z_e);
    quantize_kernel<<<(M_ROWS + 63) / 64, 256, 0, stream>>>(z_e, codebook, z_q, idxs);
    decode_kernel<<<N_B * 32, 256, 0, stream>>>(z_q, tconv_w, tconv_b, x_rec);
}

// Round 5
// 222.858 us; speedup vs baseline: 1.9793x; 1.9793x over previous
//
#include <hip/hip_runtime.h>
#include <stdint.h>

// Problem constants
#define N_B   32
#define C_INN 8
#define L_IN  4096
#define C_LAT 64
#define K_EMB 512
#define E_DIM 64
#define L_OUT 2049                 // (4096 + 2*2 - 4)/2 + 1
#define M_ROWS (N_B * L_OUT)       // 65568

// d_out layout (flat float32, reference return order)
#define SZ_XREC (N_B * C_INN * L_IN)     // 1048576
#define SZ_ZE   (N_B * C_LAT * L_OUT)    // 4196352
#define OFF_XREC 0
#define OFF_ZE   (SZ_XREC)
#define OFF_ZQ   (OFF_ZE + SZ_ZE)
#define OFF_IDX  (OFF_ZQ + SZ_ZE)

// ---------------------------------------------------------------------------
// Encode: z_e[n][c][t] = conv_b[c] + sum_{ci,k} x[n][ci][2t-2+k] * conv_w[c][ci][k]
// 2304 blocks = 32 n x 9 t-slices x 8 channel-groups (9 blocks/CU). Each lane:
// one t, 32 x-taps in registers, 8 output channels (256 FMA). (unchanged R4)
// ---------------------------------------------------------------------------
__global__ __launch_bounds__(256) void encode_kernel(
    const float* __restrict__ x, const float* __restrict__ w,
    const float* __restrict__ b, float* __restrict__ z_e)
{
    const int blk   = blockIdx.x;        // 0..2303
    const int n     = blk / 72;
    const int rem   = blk - n * 72;
    const int slice = rem >> 3;          // 0..8
    const int cg    = rem & 7;           // channel group: c = cg*8 .. cg*8+7
    const int t     = slice * 256 + threadIdx.x;   // 0..2303
    const bool valid = (t < L_OUT);

    const float* xrow = x + (size_t)n * (C_INN * L_IN);

    float xv[C_INN][4];
    const bool fast = (t >= 1 && t <= 2047);  // 2t-2 >= 0 and 2t+1 <= 4095
    if (fast) {
#pragma unroll
        for (int ci = 0; ci < C_INN; ++ci) {
            float4 v = *(const float4*)(xrow + ci * L_IN + (2 * t - 2));
            xv[ci][0] = v.x; xv[ci][1] = v.y; xv[ci][2] = v.z; xv[ci][3] = v.w;
        }
    } else {
#pragma unroll
        for (int ci = 0; ci < C_INN; ++ci) {
#pragma unroll
            for (int k = 0; k < 4; ++k) {
                int xi = 2 * t - 2 + k;
                int xc = min(max(xi, 0), L_IN - 1);
                float v = valid ? xrow[ci * L_IN + xc] : 0.0f;
                xv[ci][k] = (xi >= 0 && xi < L_IN) ? v : 0.0f;
            }
        }
    }

    float* zcol = z_e + (size_t)n * (C_LAT * L_OUT) + t;

#pragma unroll
    for (int cj = 0; cj < 8; ++cj) {
        const int c = cg * 8 + cj;
        float a = b[c];
#pragma unroll
        for (int ci = 0; ci < C_INN; ++ci) {
            const float* wp = w + (c * C_INN + ci) * 4;  // wave-uniform
#pragma unroll
            for (int k = 0; k < 4; ++k) a += xv[ci][k] * wp[k];
        }
        if (valid) zcol[(size_t)c * L_OUT] = a;
    }
}

// ---------------------------------------------------------------------------
// Quantize, round 5: ALL inner-loop operands from LDS.
// Evidence R1-R4: fp32 FMA fed from global/scalar memory is either
// load-issue-bound (112us) or load-latency-serialized (358us); the compiler
// pipelines only LDS (lgkmcnt) operands well.
// Structure per block (64 rows, 4 waves):
//   - s_z [d][row] 16KB: z tile, staged once, conflict-free b32 reads.
//   - s_cbt [code][d] 16KB: 64-code tile, restaged 8x; compute reads are
//     wave-uniform float4 -> ds_read_b128 broadcast (conflict-free).
//   - per wave per tile: 16 codes, acc[16]; per d4: 4 z reads + 16 cb
//     broadcasts + 64 FMA -> VALU-bound (~2:1 VALU:DS cycles).
// Exact fp32 math; ascending-k compare keeps first-occurrence tie-break.
// ---------------------------------------------------------------------------
__global__ __launch_bounds__(256, 4) void quantize_kernel(
    const float* __restrict__ z_e, const float* __restrict__ cb,
    float* __restrict__ z_q, float* __restrict__ idx_out)
{
    __shared__ float s_cbh[K_EMB];                  // 0.5*||cb_k||^2  (2 KB)
    __shared__ float s_z[E_DIM * 64];               // [d][row]        (16 KB)
    __shared__ float s_cbt[64 * E_DIM];             // [code][d] tile  (16 KB)
    __shared__ unsigned long long s_best[4][64];    //                 (2 KB)

    const int tid  = threadIdx.x;
    const int wave = tid >> 6;
    const int lane = tid & 63;
    const int wq   = __builtin_amdgcn_readfirstlane(wave);  // wave-uniform

    // 0.5*||cb||^2 into LDS (each thread: 2 codes)
    for (int k = tid; k < K_EMB; k += 256) {
        const float4* cp = (const float4*)(cb + (size_t)k * E_DIM);
        float s = 0.0f;
#pragma unroll
        for (int d = 0; d < E_DIM / 4; ++d) {
            float4 v = cp[d];
            s += v.x * v.x + v.y * v.y + v.z * v.z + v.w * v.w;
        }
        s_cbh[k] = 0.5f * s;
    }

    // stage z tile: thread (row = tid&63, chans 16*(tid>>6)..+16), coalesced
    {
        const int  rl     = lane;
        const int  cbase  = wave * 16;
        const int  rr0    = blockIdx.x * 64 + rl;
        const bool act    = (rr0 < M_ROWS);
        const unsigned rr = act ? (unsigned)rr0 : 0u;
        const unsigned n  = rr / 2049u;
        const unsigned t  = rr - n * 2049u;
        const float* zp   = z_e + (size_t)n * (C_LAT * L_OUT) + t;
#pragma unroll
        for (int j = 0; j < 16; ++j) {
            const int c = cbase + j;
            s_z[c * 64 + rl] = zp[(size_t)c * L_OUT];  // bank = rl%32: free
        }
    }

    const int  r      = blockIdx.x * 64 + lane;
    const bool active = (r < M_ROWS);
    const unsigned rr = active ? (unsigned)r : 0u;
    const unsigned n  = rr / 2049u;
    const unsigned t  = rr - n * 2049u;

    float best_m = INFINITY;
    int   best_k = 0;

    for (int tt = 0; tt < 8; ++tt) {
        __syncthreads();   // first iter: covers s_z/s_cbh; later: tile reuse
        // stage 64-code tile: 1024 float4 / 256 threads = 4 each, coalesced
        {
            const float4* src = (const float4*)(cb + (size_t)tt * 64 * E_DIM);
            float4* dst = (float4*)s_cbt;
#pragma unroll
            for (int i = 0; i < 4; ++i)
                dst[tid + 256 * i] = src[tid + 256 * i];
        }
        __syncthreads();

        const int cbase = wq * 16;        // codes within tile for this wave
        float acc[16];
#pragma unroll
        for (int j = 0; j < 16; ++j) acc[j] = 0.0f;

        for (int d4 = 0; d4 < 16; ++d4) {
            const float z0 = s_z[(d4 * 4 + 0) * 64 + lane];
            const float z1 = s_z[(d4 * 4 + 1) * 64 + lane];
            const float z2 = s_z[(d4 * 4 + 2) * 64 + lane];
            const float z3 = s_z[(d4 * 4 + 3) * 64 + lane];
#pragma unroll
            for (int j = 0; j < 16; ++j) {
                // wave-uniform address -> ds_read_b128 broadcast
                const float4 cv =
                    *(const float4*)(s_cbt + (cbase + j) * E_DIM + d4 * 4);
                acc[j] += z0 * cv.x + z1 * cv.y + z2 * cv.z + z3 * cv.w;
            }
        }

#pragma unroll
        for (int j = 0; j < 16; ++j) {
            const int kg = tt * 64 + cbase + j;      // global code index
            const float m = s_cbh[kg] - acc[j];
            if (m < best_m) { best_m = m; best_k = kg; }
        }
    }

    // pack: order-preserving float bits in high 32, k in low 32
    unsigned um = __float_as_uint(best_m);
    um = (um & 0x80000000u) ? ~um : (um | 0x80000000u);
    unsigned long long packed =
        ((unsigned long long)um << 32) | (unsigned)best_k;
    if (!active) packed = ~0ULL;
    s_best[wave][lane] = packed;
    __syncthreads();

    unsigned long long p  = s_best[0][lane];
    unsigned long long q1 = s_best[1][lane];
    unsigned long long q2 = s_best[2][lane];
    unsigned long long q3 = s_best[3][lane];
    p = (q1 < p) ? q1 : p;
    p = (q2 < p) ? q2 : p;
    p = (q3 < p) ? q3 : p;
    const int fk = (int)(unsigned)p;

    if (active) {
        const float* csel = cb + (size_t)fk * E_DIM;
        float* zq = z_q + ((size_t)(n * C_LAT + wave * 16)) * L_OUT + t;
#pragma unroll
        for (int j = 0; j < 16; ++j)
            zq[(size_t)j * L_OUT] = csel[wave * 16 + j];
        if (wave == 0) idx_out[r] = (float)fk;
    }
}

// ---------------------------------------------------------------------------
// Decode (ConvTranspose1d): x_rec[n][co][t] = tconv_b[co]
//   + sum_{ci,s,k: t = 2s-2+k} z_q[n][ci][s] * tconv_w[ci][co][k]
// Round 5: 4 output channels per block (z_q read 2x total), 1024 blocks of
// 128 threads (n x 2 co-groups x 16 s-chunks) -> 4 blocks/CU, 8 waves/CU.
// ---------------------------------------------------------------------------
__global__ __launch_bounds__(128) void decode_kernel(
    const float* __restrict__ zq, const float* __restrict__ w,
    const float* __restrict__ b, float* __restrict__ xr)
{
    const int blk   = blockIdx.x;           // 0..1023
    const int chunk = blk & 15;
    const int cog   = (blk >> 4) & 1;
    const int n     = blk >> 5;
    const int s     = chunk * 128 + threadIdx.x;   // 0..2047
    const int co0   = cog * 4;

    const float* zn = zq + (size_t)n * (C_LAT * L_OUT) + s;
    float e[4], o[4];
#pragma unroll
    for (int j = 0; j < 4; ++j) { e[j] = b[co0 + j]; o[j] = e[j]; }

#pragma unroll 4
    for (int ci = 0; ci < C_LAT; ++ci) {
        const float z0 = zn[(size_t)ci * L_OUT];
        const float z1 = zn[(size_t)ci * L_OUT + 1];
        const float* wp = w + (ci * C_INN + co0) * 4;   // wave-uniform
#pragma unroll
        for (int j = 0; j < 4; ++j) {
            e[j] += z0 * wp[4 * j + 2] + z1 * wp[4 * j + 0];
            o[j] += z0 * wp[4 * j + 3] + z1 * wp[4 * j + 1];
        }
    }

#pragma unroll
    for (int j = 0; j < 4; ++j) {
        float* xrow = xr + ((size_t)(n * C_INN + co0 + j)) * L_IN;
        *(float2*)(xrow + 2 * s) = make_float2(e[j], o[j]);   // 8B aligned
    }
}

// ---------------------------------------------------------------------------
extern "C" void kernel_launch(void* const* d_in, const int* in_sizes, int n_in,
                              void* d_out, int out_size, void* d_ws, size_t ws_size,
                              hipStream_t stream) {
    const float* x        = (const float*)d_in[0];
    const float* conv_w   = (const float*)d_in[1];
    const float* conv_b   = (const float*)d_in[2];
    const float* codebook = (const float*)d_in[3];
    const float* tconv_w  = (const float*)d_in[4];
    const float* tconv_b  = (const float*)d_in[5];

    float* out   = (float*)d_out;
    float* x_rec = out + OFF_XREC;
    float* z_e   = out + OFF_ZE;
    float* z_q   = out + OFF_ZQ;
    float* idxs  = out + OFF_IDX;

    encode_kernel<<<N_B * 72, 256, 0, stream>>>(x, conv_w, conv_b, z_e);
    quantize_kernel<<<(M_ROWS + 63) / 64, 256, 0, stream>>>(z_e, codebook, z_q, idxs);
    decode_kernel<<<1024, 128, 0, stream>>>(z_q, tconv_w, tconv_b, x_rec);
}

// Round 6
// 186.175 us; speedup vs baseline: 2.3693x; 1.1970x over previous
//
#include <hip/hip_runtime.h>
#include <stdint.h>

// Problem constants
#define N_B   32
#define C_INN 8
#define L_IN  4096
#define C_LAT 64
#define K_EMB 512
#define E_DIM 64
#define L_OUT 2049                 // (4096 + 2*2 - 4)/2 + 1
#define M_ROWS (N_B * L_OUT)       // 65568

// d_out layout (flat float32, reference return order)
#define SZ_XREC (N_B * C_INN * L_IN)     // 1048576
#define SZ_ZE   (N_B * C_LAT * L_OUT)    // 4196352
#define OFF_XREC 0
#define OFF_ZE   (SZ_XREC)
#define OFF_ZQ   (OFF_ZE + SZ_ZE)
#define OFF_IDX  (OFF_ZQ + SZ_ZE)

typedef short short8 __attribute__((ext_vector_type(8)));
typedef float f32x4  __attribute__((ext_vector_type(4)));

__device__ __forceinline__ unsigned short rne16(float f) {
    unsigned u = __float_as_uint(f);
    return (unsigned short)((u + 0x7FFFu + ((u >> 16) & 1u)) >> 16);
}
__device__ __forceinline__ float frombits16(unsigned short h) {
    return __uint_as_float(((unsigned)h) << 16);
}
// order-preserving float->u32 (monotone for all finite values)
__device__ __forceinline__ unsigned orderbits(float f) {
    unsigned u = __float_as_uint(f);
    return u ^ ((unsigned)((int)u >> 31) | 0x80000000u);
}
__device__ __forceinline__ float unpackf(unsigned ub) {
    unsigned u = (ub & 0x80000000u) ? (ub ^ 0x80000000u) : ~ub;
    return __uint_as_float(u);
}

// ---------------------------------------------------------------------------
// Prep: swizzle codebook into MFMA B-fragment order, split into bf16 hi/lo.
// Layout (u16 units): frag[((ntile*2+ks)*2+h)*512 + lane*8 + j] =
//   split_h(cb[ntile*16 + lane%16][ks*32 + (lane/16)*8 + j])
// Total 65536 u16 = 131072 B in d_ws.
// ---------------------------------------------------------------------------
__global__ __launch_bounds__(256) void prep_kernel(
    const float* __restrict__ cb, unsigned short* __restrict__ frag)
{
    const int ntile = blockIdx.x;        // 0..31
    const int t     = threadIdx.x;
    const int lane  = t & 63;
    const int ks    = (t >> 6) & 1;
    const int h     = t >> 7;            // 0 = hi, 1 = lo
    const int code  = ntile * 16 + (lane & 15);
    const int k0    = ks * 32 + (lane >> 4) * 8;

    const float* src = cb + (size_t)code * E_DIM + k0;
    unsigned short out[8];
#pragma unroll
    for (int j = 0; j < 8; ++j) {
        const float v = src[j];
        const unsigned short hb = rne16(v);
        out[j] = h ? rne16(v - frombits16(hb)) : hb;
    }
    short8 v8;
#pragma unroll
    for (int j = 0; j < 8; ++j) v8[j] = (short)out[j];
    short8* dst = (short8*)(frag + (((size_t)(ntile * 2 + ks) * 2 + h) * 512 + lane * 8));
    *dst = v8;
}

// ---------------------------------------------------------------------------
// Encode: z_e[n][c][t] = conv_b[c] + sum_{ci,k} x[n][ci][2t-2+k] * conv_w[c][ci][k]
// 2304 blocks = 32 n x 9 t-slices x 8 channel-groups. (unchanged R4/R5)
// ---------------------------------------------------------------------------
__global__ __launch_bounds__(256) void encode_kernel(
    const float* __restrict__ x, const float* __restrict__ w,
    const float* __restrict__ b, float* __restrict__ z_e)
{
    const int blk   = blockIdx.x;
    const int n     = blk / 72;
    const int rem   = blk - n * 72;
    const int slice = rem >> 3;
    const int cg    = rem & 7;
    const int t     = slice * 256 + threadIdx.x;
    const bool valid = (t < L_OUT);

    const float* xrow = x + (size_t)n * (C_INN * L_IN);

    float xv[C_INN][4];
    const bool fast = (t >= 1 && t <= 2047);
    if (fast) {
#pragma unroll
        for (int ci = 0; ci < C_INN; ++ci) {
            float4 v = *(const float4*)(xrow + ci * L_IN + (2 * t - 2));
            xv[ci][0] = v.x; xv[ci][1] = v.y; xv[ci][2] = v.z; xv[ci][3] = v.w;
        }
    } else {
#pragma unroll
        for (int ci = 0; ci < C_INN; ++ci) {
#pragma unroll
            for (int k = 0; k < 4; ++k) {
                int xi = 2 * t - 2 + k;
                int xc = min(max(xi, 0), L_IN - 1);
                float v = valid ? xrow[ci * L_IN + xc] : 0.0f;
                xv[ci][k] = (xi >= 0 && xi < L_IN) ? v : 0.0f;
            }
        }
    }

    float* zcol = z_e + (size_t)n * (C_LAT * L_OUT) + t;

#pragma unroll
    for (int cj = 0; cj < 8; ++cj) {
        const int c = cg * 8 + cj;
        float a = b[c];
#pragma unroll
        for (int ci = 0; ci < C_INN; ++ci) {
            const float* wp = w + (c * C_INN + ci) * 4;  // wave-uniform
#pragma unroll
            for (int k = 0; k < 4; ++k) a += xv[ci][k] * wp[k];
        }
        if (valid) zcol[(size_t)c * L_OUT] = a;
    }
}

// ---------------------------------------------------------------------------
// Quantize, round 6: MFMA bf16x3 screen + exact fp32 rescore.
// R1-R5 evidence: fp32-VALU distance GEMM is bounded by operand delivery
// (global-issue 112us / latency 358us / LDS-issue 147us). MFMA sidesteps it.
// Screen: dot(z,c) ~ zh*ch + zh*cl + zl*ch via mfma_f32_16x16x32_bf16 into one
// fp32 acc (err ~3e-5 RMS). Per lane keep top-2 per 16-code class; reduce to
// per-row approx min m*; exact-fp32 rescore every candidate within m*+0.02
// (covers >>10 sigma of screen error; true argmin provably qualifies).
// Block: 64 rows, 4 waves; wave w screens rows w*16..w*16+15 x all 512 codes.
// B-frags from d_ws direct (L2-resident, coalesced dwordx4, no barriers).
// ---------------------------------------------------------------------------
__global__ __launch_bounds__(256, 3) void quantize_kernel(
    const float* __restrict__ z_e, const float* __restrict__ cb,
    const unsigned short* __restrict__ frag,
    float* __restrict__ z_q, float* __restrict__ idx_out)
{
    __shared__ float s_zrow[64][68];                 // z tile fp32, padded (17.4 KB)
    __shared__ float s_cbh[K_EMB];                   // 0.5*||c||^2 exact   (2 KB)
    __shared__ unsigned long long s_cand[64][16][2]; // top2 per class      (16 KB)
    __shared__ unsigned long long s_final[64];       // exact argmin        (0.5 KB)
    __shared__ float s_mstar[64];                    // approx min          (0.25 KB)

    const int tid  = threadIdx.x;
    const int wave = tid >> 6;
    const int lane = tid & 63;

    // 0.5*||c||^2 (exact fp32, fixed order)
    for (int k = tid; k < K_EMB; k += 256) {
        const float4* cp = (const float4*)(cb + (size_t)k * E_DIM);
        float s = 0.0f;
#pragma unroll
        for (int d = 0; d < E_DIM / 4; ++d) {
            float4 v = cp[d];
            s += v.x * v.x + v.y * v.y + v.z * v.z + v.w * v.w;
        }
        s_cbh[k] = 0.5f * s;
    }
    if (tid < 64) s_final[tid] = ~0ULL;

    // stage z rows (fp32): row = tid&63, c = j*4 + wave  (coalesced over t)
    {
        const int row = tid & 63;
        const int r   = blockIdx.x * 64 + row;
        const bool act = (r < M_ROWS);
        const unsigned rr = act ? (unsigned)r : 0u;
        const unsigned n  = rr / 2049u;
        const unsigned tt = rr - n * 2049u;
        const float* zp = z_e + (size_t)n * (C_LAT * L_OUT) + tt;
#pragma unroll
        for (int j = 0; j < 16; ++j) {
            const int c = j * 4 + wave;
            s_zrow[row][c] = zp[(size_t)c * L_OUT];
        }
    }
    __syncthreads();

    // A-fragments (this lane's row of the wave's 16-row strip), bf16 hi/lo
    const int m = lane & 15, q = lane >> 4;
    short8 Ah[2], Al[2];
#pragma unroll
    for (int ks = 0; ks < 2; ++ks) {
#pragma unroll
        for (int j = 0; j < 8; ++j) {
            const float v = s_zrow[wave * 16 + m][ks * 32 + q * 8 + j];
            const unsigned short hb = rne16(v);
            Ah[ks][j] = (short)hb;
            Al[ks][j] = (short)rne16(v - frombits16(hb));
        }
    }

    // screen all 32 code-tiles
    unsigned long long ca[4], cb2[4];                // top-2 (a<=b) per C row
#pragma unroll
    for (int r4 = 0; r4 < 4; ++r4) { ca[r4] = ~0ULL; cb2[r4] = ~0ULL; }

    const short8* B8 = (const short8*)frag;
#pragma unroll 2
    for (int ntile = 0; ntile < 32; ++ntile) {
        const short8 Bh0 = B8[((ntile * 2 + 0) * 2 + 0) * 64 + lane];
        const short8 Bl0 = B8[((ntile * 2 + 0) * 2 + 1) * 64 + lane];
        const short8 Bh1 = B8[((ntile * 2 + 1) * 2 + 0) * 64 + lane];
        const short8 Bl1 = B8[((ntile * 2 + 1) * 2 + 1) * 64 + lane];

        f32x4 acc = {0.0f, 0.0f, 0.0f, 0.0f};
        acc = __builtin_amdgcn_mfma_f32_16x16x32_bf16(Ah[0], Bh0, acc, 0, 0, 0);
        acc = __builtin_amdgcn_mfma_f32_16x16x32_bf16(Ah[0], Bl0, acc, 0, 0, 0);
        acc = __builtin_amdgcn_mfma_f32_16x16x32_bf16(Al[0], Bh0, acc, 0, 0, 0);
        acc = __builtin_amdgcn_mfma_f32_16x16x32_bf16(Ah[1], Bh1, acc, 0, 0, 0);
        acc = __builtin_amdgcn_mfma_f32_16x16x32_bf16(Ah[1], Bl1, acc, 0, 0, 0);
        acc = __builtin_amdgcn_mfma_f32_16x16x32_bf16(Al[1], Bh1, acc, 0, 0, 0);

        const int code = ntile * 16 + m;             // C col = lane&15
        const float ch = s_cbh[code];
#pragma unroll
        for (int r4 = 0; r4 < 4; ++r4) {             // C row = q*4 + r4
            const float dist = ch - acc[r4];
            const unsigned long long x =
                ((unsigned long long)orderbits(dist) << 32) | (unsigned)code;
            const unsigned long long mx = (ca[r4] > x) ? ca[r4] : x;
            ca[r4]  = (ca[r4] > x) ? x : ca[r4];
            cb2[r4] = (cb2[r4] > mx) ? mx : cb2[r4];
        }
    }

    // deposit candidates: row = wave*16 + q*4 + r4, class = m
#pragma unroll
    for (int r4 = 0; r4 < 4; ++r4) {
        s_cand[wave * 16 + q * 4 + r4][m][0] = ca[r4];
        s_cand[wave * 16 + q * 4 + r4][m][1] = cb2[r4];
    }
    __syncthreads();

    // per-row approx min
    if (tid < 64) {
        unsigned long long mn = ~0ULL;
#pragma unroll 4
        for (int i = 0; i < 32; ++i) {
            const unsigned long long v = s_cand[tid][i >> 1][i & 1];
            mn = (v < mn) ? v : mn;
        }
        s_mstar[tid] = unpackf((unsigned)(mn >> 32));
    }
    __syncthreads();

    // exact rescore of candidates within m* + eps (expected ~1-2 per row)
    {
        const int row = tid >> 2;                    // 4 threads per row
        const float thr = s_mstar[row] + 0.02f;
#pragma unroll
        for (int j = 0; j < 8; ++j) {
            const int sl = (tid & 3) * 8 + j;        // 0..31
            const unsigned long long cand = s_cand[row][sl >> 1][sl & 1];
            const unsigned code = (unsigned)cand;
            const float fa = unpackf((unsigned)(cand >> 32));
            if (fa <= thr) {                         // NaN (empty slot) fails
                const float4* c4 = (const float4*)(cb + (size_t)code * E_DIM);
                float dot = 0.0f;
#pragma unroll
                for (int d4 = 0; d4 < 16; ++d4) {
                    const float4 cv = c4[d4];
                    dot += s_zrow[row][d4 * 4 + 0] * cv.x +
                           s_zrow[row][d4 * 4 + 1] * cv.y +
                           s_zrow[row][d4 * 4 + 2] * cv.z +
                           s_zrow[row][d4 * 4 + 3] * cv.w;
                }
                const float mex = s_cbh[code] - dot;
                const unsigned long long px =
                    ((unsigned long long)orderbits(mex) << 32) | code;
                atomicMin(&s_final[row], px);
            }
        }
    }
    __syncthreads();

    // epilogue: z_q gather + coalesced write; idx as float
    {
        const int row = tid & 63;
        const int r   = blockIdx.x * 64 + row;
        if (r < M_ROWS) {
            const unsigned n  = (unsigned)r / 2049u;
            const unsigned tt = (unsigned)r - n * 2049u;
            const unsigned fk = (unsigned)s_final[row];
            const float* csel = cb + (size_t)fk * E_DIM;
            float* zq = z_q + (size_t)n * (C_LAT * L_OUT) + tt;
#pragma unroll
            for (int j = 0; j < 16; ++j) {
                const int c = j * 4 + wave;
                zq[(size_t)c * L_OUT] = csel[c];
            }
            if (tid < 64) idx_out[r] = (float)fk;
        }
    }
}

// ---------------------------------------------------------------------------
// Decode (ConvTranspose1d), round 6: LDS-staged. Block = (n, 128-wide s-chunk):
// stage z_q[n][all 64 ci][s0..s0+128] into LDS once (z_q read exactly once
// from HBM), then each of 128 threads computes all 8 co for its s (t=2s,2s+1).
// 512 blocks x 128 thr.
// ---------------------------------------------------------------------------
__global__ __launch_bounds__(128) void decode_kernel(
    const float* __restrict__ zq, const float* __restrict__ w,
    const float* __restrict__ b, float* __restrict__ xr)
{
    __shared__ float s_zq[C_LAT][130];   // 129 used, pad to 130 (33.3 KB)

    const int blk   = blockIdx.x;        // 0..511
    const int chunk = blk & 15;
    const int n     = blk >> 4;
    const int s0    = chunk * 128;
    const int tid   = threadIdx.x;

    const float* zn = zq + (size_t)n * (C_LAT * L_OUT);
#pragma unroll 5
    for (int it = 0; it < 65; ++it) {
        const int idx = it * 128 + tid;          // 0..8319 = 64*130
        const int c   = idx / 130;
        const int sl  = idx - c * 130;
        if (sl < 129) s_zq[c][sl] = zn[(size_t)c * L_OUT + s0 + sl];
    }
    __syncthreads();

    float e[C_INN], o[C_INN];
#pragma unroll
    for (int co = 0; co < C_INN; ++co) { e[co] = b[co]; o[co] = e[co]; }

    for (int ci = 0; ci < C_LAT; ++ci) {
        const float z0 = s_zq[ci][tid];
        const float z1 = s_zq[ci][tid + 1];
        const float* wp = w + ci * (C_INN * 4);  // wave-uniform -> SGPR
#pragma unroll
        for (int co = 0; co < C_INN; ++co) {
            e[co] += z0 * wp[4 * co + 2] + z1 * wp[4 * co + 0];
            o[co] += z0 * wp[4 * co + 3] + z1 * wp[4 * co + 1];
        }
    }

    const int s = s0 + tid;
#pragma unroll
    for (int co = 0; co < C_INN; ++co) {
        float* xrow = xr + ((size_t)(n * C_INN + co)) * L_IN;
        *(float2*)(xrow + 2 * s) = make_float2(e[co], o[co]);
    }
}

// ---------------------------------------------------------------------------
extern "C" void kernel_launch(void* const* d_in, const int* in_sizes, int n_in,
                              void* d_out, int out_size, void* d_ws, size_t ws_size,
                              hipStream_t stream) {
    const float* x        = (const float*)d_in[0];
    const float* conv_w   = (const float*)d_in[1];
    const float* conv_b   = (const float*)d_in[2];
    const float* codebook = (const float*)d_in[3];
    const float* tconv_w  = (const float*)d_in[4];
    const float* tconv_b  = (const float*)d_in[5];

    float* out   = (float*)d_out;
    float* x_rec = out + OFF_XREC;
    float* z_e   = out + OFF_ZE;
    float* z_q   = out + OFF_ZQ;
    float* idxs  = out + OFF_IDX;

    unsigned short* frag = (unsigned short*)d_ws;   // 131072 B

    prep_kernel<<<32, 256, 0, stream>>>(codebook, frag);
    encode_kernel<<<N_B * 72, 256, 0, stream>>>(x, conv_w, conv_b, z_e);
    quantize_kernel<<<(M_ROWS + 63) / 64, 256, 0, stream>>>(z_e, codebook, frag, z_q, idxs);
    decode_kernel<<<512, 128, 0, stream>>>(z_q, tconv_w, tconv_b, x_rec);
}

// Round 7
// 153.310 us; speedup vs baseline: 2.8773x; 1.2144x over previous
//
#include <hip/hip_runtime.h>
#include <stdint.h>

// Problem constants
#define N_B   32
#define C_INN 8
#define L_IN  4096
#define C_LAT 64
#define K_EMB 512
#define E_DIM 64
#define L_OUT 2049                 // (4096 + 2*2 - 4)/2 + 1
#define M_ROWS (N_B * L_OUT)       // 65568

// d_out layout (flat float32, reference return order)
#define SZ_XREC (N_B * C_INN * L_IN)     // 1048576
#define SZ_ZE   (N_B * C_LAT * L_OUT)    // 4196352
#define OFF_XREC 0
#define OFF_ZE   (SZ_XREC)
#define OFF_ZQ   (OFF_ZE + SZ_ZE)
#define OFF_IDX  (OFF_ZQ + SZ_ZE)

typedef short short8 __attribute__((ext_vector_type(8)));
typedef float f32x4  __attribute__((ext_vector_type(4)));

__device__ __forceinline__ unsigned short rne16(float f) {
    unsigned u = __float_as_uint(f);
    return (unsigned short)((u + 0x7FFFu + ((u >> 16) & 1u)) >> 16);
}
__device__ __forceinline__ float frombits16(unsigned short h) {
    return __uint_as_float(((unsigned)h) << 16);
}
// order-preserving float->u32 (monotone for all finite values)
__device__ __forceinline__ unsigned orderbits(float f) {
    unsigned u = __float_as_uint(f);
    return u ^ ((unsigned)((int)u >> 31) | 0x80000000u);
}
__device__ __forceinline__ float unpackf(unsigned ub) {
    unsigned u = (ub & 0x80000000u) ? (ub ^ 0x80000000u) : ~ub;
    return __uint_as_float(u);
}

// ---------------------------------------------------------------------------
// Prep: (a) swizzle codebook into MFMA B-fragment order, split bf16 hi/lo
// (layout as R6, validated); (b) 0.5*||c||^2 per code into ws (same float4
// summation order as the R6 in-kernel version -> bit-identical dists).
// ---------------------------------------------------------------------------
__global__ __launch_bounds__(256) void prep_kernel(
    const float* __restrict__ cb, unsigned short* __restrict__ frag,
    float* __restrict__ cbh)
{
    const int ntile = blockIdx.x;        // 0..31
    const int t     = threadIdx.x;
    const int lane  = t & 63;
    const int ks    = (t >> 6) & 1;
    const int h     = t >> 7;            // 0 = hi, 1 = lo
    const int code  = ntile * 16 + (lane & 15);
    const int k0    = ks * 32 + (lane >> 4) * 8;

    const float* src = cb + (size_t)code * E_DIM + k0;
    unsigned short out[8];
#pragma unroll
    for (int j = 0; j < 8; ++j) {
        const float v = src[j];
        const unsigned short hb = rne16(v);
        out[j] = h ? rne16(v - frombits16(hb)) : hb;
    }
    short8 v8;
#pragma unroll
    for (int j = 0; j < 8; ++j) v8[j] = (short)out[j];
    short8* dst = (short8*)(frag + (((size_t)(ntile * 2 + ks) * 2 + h) * 512 + lane * 8));
    *dst = v8;

    if (t < 16) {
        const int c2 = ntile * 16 + t;
        const float4* cp = (const float4*)(cb + (size_t)c2 * E_DIM);
        float s = 0.0f;
#pragma unroll
        for (int d = 0; d < E_DIM / 4; ++d) {
            float4 v = cp[d];
            s += v.x * v.x + v.y * v.y + v.z * v.z + v.w * v.w;
        }
        cbh[c2] = 0.5f * s;
    }
}

// ---------------------------------------------------------------------------
// Fused encode+quantize, round 7.
// Phase 1 (encode): thread (row = tid&63, cg = wave) computes z_e for its row
//   and 16 channels c = cg*16+j (512 FMA, wave-uniform weights), writes both
//   global z_e and LDS s_z[c][row]. Kills the separate encode kernel, its 8x
//   redundant x reads, and quantize's 16MB z_e read.
// Phase 2 (screen): R6's validated bf16x3 MFMA screen, with:
//   - s_z[d][row+pad2]: all access phases <=2-way banked (R6's [row][68] was
//     8-way on the A-build -> 1.9M conflict cycles);
//   - 0.5*||c||^2 loaded from prep (R6 recomputed 128KB per block);
//   - two independent 3-MFMA chains (acc0/acc1) instead of one 6-chain.
// Phase 3: per-row approx min -> exact fp32 rescore within m*+0.02 ->
//   ascending-code tie-break (identical semantics to R6, which passed).
// ---------------------------------------------------------------------------
__global__ __launch_bounds__(256, 4) void quantize_kernel(
    const float* __restrict__ x, const float* __restrict__ conv_w,
    const float* __restrict__ conv_b, const float* __restrict__ cb,
    const unsigned short* __restrict__ frag, const float* __restrict__ cbh_ws,
    float* __restrict__ z_e, float* __restrict__ z_q,
    float* __restrict__ idx_out)
{
    __shared__ float s_z[E_DIM][66];                 // [chan][row] pad2 (16.9 KB)
    __shared__ float s_cbh[K_EMB];                   //                  (2 KB)
    __shared__ unsigned long long s_cand[64][16][2]; // top2 per class   (16 KB)
    __shared__ unsigned long long s_final[64];       //                  (0.5 KB)
    __shared__ float s_mstar[64];                    //                  (0.25 KB)

    const int tid  = threadIdx.x;
    const int wave = tid >> 6;
    const int lane = tid & 63;

    // cbh from prep
    s_cbh[tid]       = cbh_ws[tid];
    s_cbh[tid + 256] = cbh_ws[tid + 256];
    if (tid < 64) s_final[tid] = ~0ULL;

    // ---- Phase 1: encode my row's 16 channels ----
    const int  row    = lane;
    const int  r      = blockIdx.x * 64 + row;
    const bool active = (r < M_ROWS);
    const unsigned rr = active ? (unsigned)r : 0u;
    const unsigned n  = rr / 2049u;
    const unsigned tt = rr - n * 2049u;

    {
        const float* xrow = x + (size_t)n * (C_INN * L_IN);
        float xv[C_INN][4];
        const bool fast = (tt >= 1 && tt <= 2047);
        if (fast) {
#pragma unroll
            for (int ci = 0; ci < C_INN; ++ci) {
                float4 v = *(const float4*)(xrow + ci * L_IN + (2 * (int)tt - 2));
                xv[ci][0] = v.x; xv[ci][1] = v.y; xv[ci][2] = v.z; xv[ci][3] = v.w;
            }
        } else {
#pragma unroll
            for (int ci = 0; ci < C_INN; ++ci) {
#pragma unroll
                for (int k = 0; k < 4; ++k) {
                    int xi = 2 * (int)tt - 2 + k;
                    int xc = min(max(xi, 0), L_IN - 1);
                    float v = xrow[ci * L_IN + xc];
                    xv[ci][k] = (xi >= 0 && xi < L_IN) ? v : 0.0f;
                }
            }
        }
        float* zcol = z_e + (size_t)n * (C_LAT * L_OUT) + tt;
#pragma unroll
        for (int j = 0; j < 16; ++j) {
            const int c = wave * 16 + j;             // wave-uniform channel
            float a = conv_b[c];
#pragma unroll
            for (int ci = 0; ci < C_INN; ++ci) {
                const float* wp = conv_w + (c * C_INN + ci) * 4;  // uniform
#pragma unroll
                for (int k = 0; k < 4; ++k) a += xv[ci][k] * wp[k];
            }
            s_z[c][row] = a;                         // 2-way banked: free
            if (active) zcol[(size_t)c * L_OUT] = a;
        }
    }
    __syncthreads();

    // ---- Phase 2: bf16x3 MFMA screen ----
    const int m = lane & 15, q = lane >> 4;
    short8 Ah[2], Al[2];
#pragma unroll
    for (int ks = 0; ks < 2; ++ks) {
#pragma unroll
        for (int j = 0; j < 8; ++j) {
            const float v = s_z[ks * 32 + q * 8 + j][wave * 16 + m];
            const unsigned short hb = rne16(v);
            Ah[ks][j] = (short)hb;
            Al[ks][j] = (short)rne16(v - frombits16(hb));
        }
    }

    unsigned long long ca[4], cb2[4];                // top-2 (a<=b) per C row
#pragma unroll
    for (int r4 = 0; r4 < 4; ++r4) { ca[r4] = ~0ULL; cb2[r4] = ~0ULL; }

    const short8* B8 = (const short8*)frag;
#pragma unroll 2
    for (int ntile = 0; ntile < 32; ++ntile) {
        const short8 Bh0 = B8[((ntile * 2 + 0) * 2 + 0) * 64 + lane];
        const short8 Bl0 = B8[((ntile * 2 + 0) * 2 + 1) * 64 + lane];
        const short8 Bh1 = B8[((ntile * 2 + 1) * 2 + 0) * 64 + lane];
        const short8 Bl1 = B8[((ntile * 2 + 1) * 2 + 1) * 64 + lane];

        f32x4 acc0 = {0.0f, 0.0f, 0.0f, 0.0f};
        f32x4 acc1 = {0.0f, 0.0f, 0.0f, 0.0f};
        acc0 = __builtin_amdgcn_mfma_f32_16x16x32_bf16(Ah[0], Bh0, acc0, 0, 0, 0);
        acc1 = __builtin_amdgcn_mfma_f32_16x16x32_bf16(Ah[1], Bh1, acc1, 0, 0, 0);
        acc0 = __builtin_amdgcn_mfma_f32_16x16x32_bf16(Ah[0], Bl0, acc0, 0, 0, 0);
        acc1 = __builtin_amdgcn_mfma_f32_16x16x32_bf16(Ah[1], Bl1, acc1, 0, 0, 0);
        acc0 = __builtin_amdgcn_mfma_f32_16x16x32_bf16(Al[0], Bh0, acc0, 0, 0, 0);
        acc1 = __builtin_amdgcn_mfma_f32_16x16x32_bf16(Al[1], Bh1, acc1, 0, 0, 0);

        const int code = ntile * 16 + m;             // C col = lane&15
        const float ch = s_cbh[code];
#pragma unroll
        for (int r4 = 0; r4 < 4; ++r4) {             // C row = q*4 + r4
            const float dist = ch - (acc0[r4] + acc1[r4]);
            const unsigned long long xx =
                ((unsigned long long)orderbits(dist) << 32) | (unsigned)code;
            const unsigned long long mx = (ca[r4] > xx) ? ca[r4] : xx;
            ca[r4]  = (ca[r4] > xx) ? xx : ca[r4];
            cb2[r4] = (cb2[r4] > mx) ? mx : cb2[r4];
        }
    }

#pragma unroll
    for (int r4 = 0; r4 < 4; ++r4) {
        s_cand[wave * 16 + q * 4 + r4][m][0] = ca[r4];
        s_cand[wave * 16 + q * 4 + r4][m][1] = cb2[r4];
    }
    __syncthreads();

    // per-row approx min
    if (tid < 64) {
        unsigned long long mn = ~0ULL;
#pragma unroll 4
        for (int i = 0; i < 32; ++i) {
            const unsigned long long v = s_cand[tid][i >> 1][i & 1];
            mn = (v < mn) ? v : mn;
        }
        s_mstar[tid] = unpackf((unsigned)(mn >> 32));
    }
    __syncthreads();

    // exact rescore of candidates within m* + eps (expected ~1-2 per row)
    {
        const int rw  = tid >> 2;                    // 4 threads per row
        const float thr = s_mstar[rw] + 0.02f;
#pragma unroll
        for (int j = 0; j < 8; ++j) {
            const int sl = (tid & 3) * 8 + j;        // 0..31
            const unsigned long long cand = s_cand[rw][sl >> 1][sl & 1];
            const unsigned code = (unsigned)cand;
            const float fa = unpackf((unsigned)(cand >> 32));
            if (fa <= thr) {                         // NaN (empty slot) fails
                const float4* c4 = (const float4*)(cb + (size_t)code * E_DIM);
                float dot = 0.0f;
#pragma unroll
                for (int d4 = 0; d4 < 16; ++d4) {
                    const float4 cv = c4[d4];
                    dot += s_z[d4 * 4 + 0][rw] * cv.x +
                           s_z[d4 * 4 + 1][rw] * cv.y +
                           s_z[d4 * 4 + 2][rw] * cv.z +
                           s_z[d4 * 4 + 3][rw] * cv.w;
                }
                const float mex = s_cbh[code] - dot;
                const unsigned long long px =
                    ((unsigned long long)orderbits(mex) << 32) | code;
                atomicMin(&s_final[rw], px);
            }
        }
    }
    __syncthreads();

    // epilogue: z_q gather + coalesced write; idx as float
    if (active) {
        const unsigned fk = (unsigned)s_final[row];
        const float* csel = cb + (size_t)fk * E_DIM;
        float* zq = z_q + (size_t)n * (C_LAT * L_OUT) + tt;
#pragma unroll
        for (int j = 0; j < 16; ++j) {
            const int c = j * 4 + wave;
            zq[(size_t)c * L_OUT] = csel[c];
        }
        if (tid < 64) idx_out[r] = (float)fk;
    }
}

// ---------------------------------------------------------------------------
// Decode (ConvTranspose1d): x_rec[n][co][t] = tconv_b[co]
//   + sum_{ci,s,k: t = 2s-2+k} z_q[n][ci][s] * tconv_w[ci][co][k]
// R5 shape (proven): 4 output channels per block, 1024 blocks of 128 threads
// (n x 2 co-groups x 16 s-chunks) -> 8 waves/CU. R6's LDS-staged variant
// (1 wave/SIMD) regressed ~30-40us -> reverted.
// ---------------------------------------------------------------------------
__global__ __launch_bounds__(128) void decode_kernel(
    const float* __restrict__ zq, const float* __restrict__ w,
    const float* __restrict__ b, float* __restrict__ xr)
{
    const int blk   = blockIdx.x;           // 0..1023
    const int chunk = blk & 15;
    const int cog   = (blk >> 4) & 1;
    const int n     = blk >> 5;
    const int s     = chunk * 128 + threadIdx.x;   // 0..2047
    const int co0   = cog * 4;

    const float* zn = zq + (size_t)n * (C_LAT * L_OUT) + s;
    float e[4], o[4];
#pragma unroll
    for (int j = 0; j < 4; ++j) { e[j] = b[co0 + j]; o[j] = e[j]; }

#pragma unroll 4
    for (int ci = 0; ci < C_LAT; ++ci) {
        const float z0 = zn[(size_t)ci * L_OUT];
        const float z1 = zn[(size_t)ci * L_OUT + 1];
        const float* wp = w + (ci * C_INN + co0) * 4;   // wave-uniform
#pragma unroll
        for (int j = 0; j < 4; ++j) {
            e[j] += z0 * wp[4 * j + 2] + z1 * wp[4 * j + 0];
            o[j] += z0 * wp[4 * j + 3] + z1 * wp[4 * j + 1];
        }
    }

#pragma unroll
    for (int j = 0; j < 4; ++j) {
        float* xrow = xr + ((size_t)(n * C_INN + co0 + j)) * L_IN;
        *(float2*)(xrow + 2 * s) = make_float2(e[j], o[j]);   // 8B aligned
    }
}

// ---------------------------------------------------------------------------
extern "C" void kernel_launch(void* const* d_in, const int* in_sizes, int n_in,
                              void* d_out, int out_size, void* d_ws, size_t ws_size,
                              hipStream_t stream) {
    const float* x        = (const float*)d_in[0];
    const float* conv_w   = (const float*)d_in[1];
    const float* conv_b   = (const float*)d_in[2];
    const float* codebook = (const float*)d_in[3];
    const float* tconv_w  = (const float*)d_in[4];
    const float* tconv_b  = (const float*)d_in[5];

    float* out   = (float*)d_out;
    float* x_rec = out + OFF_XREC;
    float* z_e   = out + OFF_ZE;
    float* z_q   = out + OFF_ZQ;
    float* idxs  = out + OFF_IDX;

    unsigned short* frag = (unsigned short*)d_ws;        // 131072 B
    float*          cbh  = (float*)(frag + 65536);       // + 2048 B

    prep_kernel<<<32, 256, 0, stream>>>(codebook, frag, cbh);
    quantize_kernel<<<(M_ROWS + 63) / 64, 256, 0, stream>>>(
        x, conv_w, conv_b, codebook, frag, cbh, z_e, z_q, idxs);
    decode_kernel<<<1024, 128, 0, stream>>>(z_q, tconv_w, tconv_b, x_rec);
}